// Round 3
// baseline (7310.323 us; speedup 1.0000x reference)
//
#include <hip/hip_runtime.h>
#include <cstdint>
#include <cstddef>

// Problem constants (B,T,H,E) = (64,256,1024,1024)
constexpr int B_ = 64;
constexpr int T_ = 256;
constexpr int H_ = 1024;
constexpr int E_ = 1024;
constexpr int G3 = 3 * H_; // 3072 stacked gate rows [r; z; n]

// Async global->LDS, 16B per lane. LDS dest must be wave-uniform; HW writes
// lane i at lds + i*16. Global src is per-lane (guide §5).
__device__ __forceinline__ void load_lds16(const float* g, float* l) {
  __builtin_amdgcn_global_load_lds((const __attribute__((address_space(1))) void*)g,
                                   (__attribute__((address_space(3))) void*)l,
                                   16, 0, 0);
}

// ---------------------------------------------------------------------------
// Kernel 1: x_gates GEMM (SGEMM-NT, fp32)
//   C[t][b][g] = sum_k x[(b*T+t)][k] * w_ih[g][k] + b_ih[g]
// Stored t-major ([256][64][3072]) so each scan step reads one contiguous slab.
// 128x128x32 tile, 256 threads, 8x8 micro-tile. v2: async reg-prefetch of the
// next K-tile (T14 split: loads fly during compute, consumed by next ds_write)
// + launch_bounds(256,2) for >=2 blocks/CU of wave-level overlap.
// ---------------------------------------------------------------------------
__global__ __launch_bounds__(256, 2) void xgates_gemm(
    const float* __restrict__ A,    // x  [16384][1024]
    const float* __restrict__ Bw,   // w_ih [3072][1024]
    const float* __restrict__ bias, // b_ih [3072]
    float* __restrict__ C)          // [256][64][3072]
{
  constexpr int BM = 128, BN = 128, BK = 32, K = 1024;
  __shared__ float As[BK][BM + 4];
  __shared__ float Bs[BK][BN + 4];
  const int bm = blockIdx.x * BM;
  const int bn = blockIdx.y * BN;
  const int tid = threadIdx.x;
  const int tx = tid & 15;  // m-direction (16 x 8 = 128)
  const int ty = tid >> 4;  // n-direction (16 x 8 = 128)

  float acc[8][8];
#pragma unroll
  for (int i = 0; i < 8; i++)
#pragma unroll
    for (int j = 0; j < 8; j++) acc[i][j] = 0.f;

  float4 pa[4], pb[4];
  auto gload = [&](int k0) {
#pragma unroll
    for (int i = 0; i < 4; i++) {
      int idx = tid + i * 256;
      int r   = idx >> 3;         // 0..127 tile row
      int c4  = (idx & 7) * 4;    // 0..28  k offset
      pa[i] = *reinterpret_cast<const float4*>(&A[(size_t)(bm + r) * K + k0 + c4]);
      pb[i] = *reinterpret_cast<const float4*>(&Bw[(size_t)(bn + r) * K + k0 + c4]);
    }
  };

  gload(0);
  for (int k0 = 0; k0 < K; k0 += BK) {
    if (k0) __syncthreads(); // prev compute done before LDS overwrite
#pragma unroll
    for (int i = 0; i < 4; i++) {
      int idx = tid + i * 256;
      int r   = idx >> 3;
      int c4  = (idx & 7) * 4;
      As[c4 + 0][r] = pa[i].x; As[c4 + 1][r] = pa[i].y;
      As[c4 + 2][r] = pa[i].z; As[c4 + 3][r] = pa[i].w;
      Bs[c4 + 0][r] = pb[i].x; Bs[c4 + 1][r] = pb[i].y;
      Bs[c4 + 2][r] = pb[i].z; Bs[c4 + 3][r] = pb[i].w;
    }
    __syncthreads();
    if (k0 + BK < K) gload(k0 + BK); // async: consumed by NEXT iter's ds_write
#pragma unroll 8
    for (int kk = 0; kk < BK; kk++) {
      float a[8], b[8];
      *reinterpret_cast<float4*>(&a[0]) = *reinterpret_cast<const float4*>(&As[kk][tx * 8]);
      *reinterpret_cast<float4*>(&a[4]) = *reinterpret_cast<const float4*>(&As[kk][tx * 8 + 4]);
      *reinterpret_cast<float4*>(&b[0]) = *reinterpret_cast<const float4*>(&Bs[kk][ty * 8]);
      *reinterpret_cast<float4*>(&b[4]) = *reinterpret_cast<const float4*>(&Bs[kk][ty * 8 + 4]);
#pragma unroll
      for (int i = 0; i < 8; i++)
#pragma unroll
        for (int j = 0; j < 8; j++)
          acc[i][j] = fmaf(a[i], b[j], acc[i][j]);
    }
  }

  // Epilogue: bias + t-major store. m = b*256 + t  ->  row (t*64 + b).
#pragma unroll
  for (int i = 0; i < 8; i++) {
    int m = bm + tx * 8 + i;
    int b = m >> 8;
    int t = m & 255;
    float* crow = &C[((size_t)t * 64 + b) * G3 + bn + ty * 8];
#pragma unroll
    for (int j4 = 0; j4 < 2; j4++) {
      float4 v;
      v.x = acc[i][j4 * 4 + 0] + bias[bn + ty * 8 + j4 * 4 + 0];
      v.y = acc[i][j4 * 4 + 1] + bias[bn + ty * 8 + j4 * 4 + 1];
      v.z = acc[i][j4 * 4 + 2] + bias[bn + ty * 8 + j4 * 4 + 2];
      v.w = acc[i][j4 * 4 + 3] + bias[bn + ty * 8 + j4 * 4 + 3];
      *reinterpret_cast<float4*>(&crow[j4 * 4]) = v;
    }
  }
}

// ---------------------------------------------------------------------------
// Kernel 2: one GRU timestep (v3 — double-buffered global_load_lds staging).
//
// Budget per CU per step: VALU floor 6144 cyc (2.56us). v2 was single-buffered:
// 8 x (stage latency ~400cy + compute ~770cy) ~= 9.3Kcy. v3: pitch-64 LDS
// (2-way bank aliasing = free, and staging map becomes exactly linear:
// lds[idx*16B] <- ht[idx*16B]) -> global_load_lds width 16, double-buffered.
// stage(c+1) issued BEFORE compute(c); the barrier's vmcnt(0) drain lands
// after compute, so the flight is covered. Epilogue operands (uncoalesced xg
// gathers, h_prev, biases) prefetched at kernel start, hidden under k-loop.
//
// Each wave covers 4 units x 3 gates (12 FMAs per h value read); K split 8
// ways across 8 waves; partials combined via LDS; waves 0..3 finish one unit.
// Weight rows wave-uniform -> scalar s_load streams (L2/L3-resident, 12MB).
// ---------------------------------------------------------------------------
__global__ __launch_bounds__(512) void gru_step(
    const float* __restrict__ xg_t,  // [64][3072]  this timestep's slab
    const float* __restrict__ ht_in, // [1024][64]
    float* __restrict__ ht_out,      // [1024][64]
    const float* __restrict__ w_hh,  // [3072][1024]
    const float* __restrict__ b_hh)  // [3072]
{
  constexpr int KC = 128;            // k-chunk per stage
  __shared__ float h_s[2][KC][64];   // 64 KB double buffer, pitch 64 (linear)
  __shared__ float args[12][8][64];  // partials [unit*3+gate][wave][lane], 24 KB
  const int tid  = threadIdx.x;
  const int lane = tid & 63;                                 // batch index
  const int wid  = __builtin_amdgcn_readfirstlane(tid >> 6); // wave 0..7 (k-slice)
  const int u0   = blockIdx.x * 4;                           // first unit of block

  // Prefetch epilogue operands; latency hides under the k-loop.
  float xr = 0.f, xz = 0.f, xn = 0.f, hp = 0.f, br = 0.f, bz = 0.f, bn2 = 0.f;
  if (wid < 4) {
    const int u = u0 + wid;
    xr = xg_t[(size_t)lane * G3 + u];
    xz = xg_t[(size_t)lane * G3 + H_ + u];
    xn = xg_t[(size_t)lane * G3 + 2 * H_ + u];
    hp = ht_in[(size_t)u * 64 + lane];
    br = b_hh[u]; bz = b_hh[H_ + u]; bn2 = b_hh[2 * H_ + u];
  }

  // Stage one 128x64 chunk (32 KB): 8 waves x 4 instrs x 1KB, fully linear.
  auto stage = [&](int buf, int kc) {
#pragma unroll
    for (int i = 0; i < 4; i++) {
      const int row = wid * 16 + i * 4; // wave-uniform LDS base
      load_lds16(ht_in + (size_t)(kc + row) * 64 + lane * 4, &h_s[buf][row][0]);
    }
  };

  float acc[4][3];
#pragma unroll
  for (int ui = 0; ui < 4; ui++)
#pragma unroll
    for (int g = 0; g < 3; g++) acc[ui][g] = 0.f;

  stage(0, 0);
  __syncthreads(); // vmcnt(0) drained -> buf0 ready
  for (int c = 0; c < 8; c++) {
    if (c < 7) stage((c + 1) & 1, (c + 1) * KC); // async; drains at barrier below
    const int jbase = wid * 16;                  // this wave's 16-k slice
    const float* hs = &h_s[c & 1][0][0];
#pragma unroll
    for (int jj = 0; jj < 16; jj += 2) {
      float h0 = hs[(jbase + jj + 0) * 64 + lane]; // ds_read2_b32 pair, 2-way free
      float h1 = hs[(jbase + jj + 1) * 64 + lane];
      const int k = c * KC + jbase + jj;           // wave-uniform
#pragma unroll
      for (int ui = 0; ui < 4; ui++) {
#pragma unroll
        for (int g = 0; g < 3; g++) {
          const float* wrow = w_hh + ((size_t)g * H_ + u0 + ui) * H_; // uniform -> s_load
          acc[ui][g] = fmaf(h0, wrow[k + 0], acc[ui][g]);
          acc[ui][g] = fmaf(h1, wrow[k + 1], acc[ui][g]);
        }
      }
    }
    __syncthreads(); // syncs compute + drains stage(c+1)
  }

  // Cross-wave combine: every wave deposits its 12 partials.
#pragma unroll
  for (int ui = 0; ui < 4; ui++)
#pragma unroll
    for (int g = 0; g < 3; g++) args[ui * 3 + g][wid][lane] = acc[ui][g];
  __syncthreads();

  // Waves 0..3 each finish one unit.
  if (wid < 4) {
    const int u = u0 + wid;
    float hr = 0.f, hz = 0.f, hn = 0.f;
#pragma unroll
    for (int w = 0; w < 8; w++) {
      hr += args[wid * 3 + 0][w][lane];
      hz += args[wid * 3 + 1][w][lane];
      hn += args[wid * 3 + 2][w][lane];
    }
    hr += br; hz += bz; hn += bn2;
    float r = 1.f / (1.f + expf(-(xr + hr)));
    float z = 1.f / (1.f + expf(-(xz + hz)));
    float n = tanhf(xn + r * hn);
    ht_out[(size_t)u * 64 + lane] = (1.f - z) * n + z * hp;
  }
}

// ---------------------------------------------------------------------------
// Kernel 3: small FC over transposed activations (runs once -> not hot).
//   out = act( At^T @ W^T + bias ), lane = batch, wave-uniform W rows.
// ---------------------------------------------------------------------------
template <int LEAKY, int STORE_T>
__global__ __launch_bounds__(256) void fc_kernel(
    const float* __restrict__ At,   // [K][64]
    const float* __restrict__ W,    // [N][K]
    const float* __restrict__ bias, // [N]
    float* __restrict__ out,        // [N][64] if STORE_T else [64][N]
    int N, int K)
{
  constexpr int KC = 128;
  __shared__ float a_s[KC][68];
  const int tid  = threadIdx.x;
  const int lane = tid & 63;
  const int wid  = __builtin_amdgcn_readfirstlane(tid >> 6);
  const int n0   = blockIdx.x * 16 + wid * 4;

  const float* __restrict__ w0 = W + (size_t)(n0 + 0) * K;
  const float* __restrict__ w1 = W + (size_t)(n0 + 1) * K;
  const float* __restrict__ w2 = W + (size_t)(n0 + 2) * K;
  const float* __restrict__ w3 = W + (size_t)(n0 + 3) * K;

  float acc0 = 0.f, acc1 = 0.f, acc2 = 0.f, acc3 = 0.f;
  for (int kc = 0; kc < K; kc += KC) {
#pragma unroll
    for (int i = 0; i < 8; i++) {
      int idx = tid + i * 256;
      int j   = idx >> 4;
      int c4  = (idx & 15) * 4;
      *reinterpret_cast<float4*>(&a_s[j][c4]) =
          *reinterpret_cast<const float4*>(&At[(size_t)(kc + j) * 64 + c4]);
    }
    __syncthreads();
#pragma unroll 16
    for (int j = 0; j < KC; j++) {
      float av = a_s[j][lane];
      acc0 = fmaf(av, w0[kc + j], acc0);
      acc1 = fmaf(av, w1[kc + j], acc1);
      acc2 = fmaf(av, w2[kc + j], acc2);
      acc3 = fmaf(av, w3[kc + j], acc3);
    }
    __syncthreads();
  }
  float r0 = acc0 + bias[n0 + 0];
  float r1 = acc1 + bias[n0 + 1];
  float r2 = acc2 + bias[n0 + 2];
  float r3 = acc3 + bias[n0 + 3];
  if (LEAKY) {
    r0 = (r0 >= 0.f) ? r0 : 0.2f * r0;
    r1 = (r1 >= 0.f) ? r1 : 0.2f * r1;
    r2 = (r2 >= 0.f) ? r2 : 0.2f * r2;
    r3 = (r3 >= 0.f) ? r3 : 0.2f * r3;
  }
  if (STORE_T) {
    out[(size_t)(n0 + 0) * 64 + lane] = r0;
    out[(size_t)(n0 + 1) * 64 + lane] = r1;
    out[(size_t)(n0 + 2) * 64 + lane] = r2;
    out[(size_t)(n0 + 3) * 64 + lane] = r3;
  } else {
    float4 v; v.x = r0; v.y = r1; v.z = r2; v.w = r3;
    *reinterpret_cast<float4*>(&out[(size_t)lane * N + n0]) = v;
  }
}

// ---------------------------------------------------------------------------
// Launch: xgates GEMM -> 256 sequential gru_step launches (graph-captured)
// -> fc1 (leaky, transposed out) -> fc2 (normal out).
// Workspace: xg 201.3 MB + 2 h buffers + y1 (~202.1 MB total).
// ---------------------------------------------------------------------------
extern "C" void kernel_launch(void* const* d_in, const int* in_sizes, int n_in,
                              void* d_out, int out_size, void* d_ws, size_t ws_size,
                              hipStream_t stream) {
  (void)in_sizes; (void)n_in; (void)out_size; (void)ws_size;
  const float* x    = (const float*)d_in[0];
  const float* w_ih = (const float*)d_in[1];
  const float* w_hh = (const float*)d_in[2];
  const float* b_ih = (const float*)d_in[3];
  const float* b_hh = (const float*)d_in[4];
  const float* w1   = (const float*)d_in[5];
  const float* b1   = (const float*)d_in[6];
  const float* w2   = (const float*)d_in[7];
  const float* b2   = (const float*)d_in[8];
  float* out = (float*)d_out;

  float* ws = (float*)d_ws;
  float* xg = ws;                              // [256][64][3072]
  float* hA = xg + (size_t)T_ * B_ * G3;       // [1024][64] (transposed h)
  float* hB = hA + (size_t)H_ * B_;
  float* y1 = hB + (size_t)H_ * B_;            // [1024][64] (transposed fc1 out)

  // h0 = 0 (ws is poisoned 0xAA before every timed call).
  hipMemsetAsync(hA, 0, (size_t)H_ * B_ * sizeof(float), stream);

  xgates_gemm<<<dim3(128, 24), 256, 0, stream>>>(x, w_ih, b_ih, xg);

  for (int t = 0; t < T_; t++) {
    const float* hin  = (t & 1) ? hB : hA;
    float*       hout = (t & 1) ? hA : hB;
    gru_step<<<256, 512, 0, stream>>>(xg + (size_t)t * B_ * G3, hin, hout, w_hh, b_hh);
  }
  // T=256 even -> final h lives in hA.
  fc_kernel<1, 1><<<64, 256, 0, stream>>>(hA, w1, b1, y1, H_, H_);
  fc_kernel<0, 0><<<64, 256, 0, stream>>>(y1, w2, b2, out, E_, H_);
}

// Round 4
// 4059.130 us; speedup vs baseline: 1.8010x; 1.8010x over previous
//
#include <hip/hip_runtime.h>
#include <cstdint>
#include <cstddef>

// Problem constants (B,T,H,E) = (64,256,1024,1024)
constexpr int B_ = 64;
constexpr int T_ = 256;
constexpr int H_ = 1024;
constexpr int E_ = 1024;
constexpr int G3 = 3 * H_; // 3072 stacked gate rows [r; z; n]

typedef __attribute__((ext_vector_type(8))) short short8; // 8 bf16 = 4 VGPR (guide §3)
typedef __attribute__((ext_vector_type(4))) float f32x4;  // MFMA accumulator

__device__ __forceinline__ f32x4 mfma16(short8 a, short8 b, f32x4 c) {
  return __builtin_amdgcn_mfma_f32_16x16x32_bf16(a, b, c, 0, 0, 0);
}

// Split fp32 into bf16 hi + bf16 lo (RNE both). w*h with all 4 cross-products
// accumulated in f32 gives ~fp32-accurate GEMM (bf16 products are exact).
__device__ __forceinline__ void bf16_split(float f, unsigned short& hi, unsigned short& lo) {
  unsigned u = __float_as_uint(f);
  unsigned r = u + 0x7fff + ((u >> 16) & 1);
  hi = (unsigned short)(r >> 16);
  float fhi = __uint_as_float((unsigned)hi << 16);
  float res = f - fhi;
  unsigned v = __float_as_uint(res);
  unsigned s = v + 0x7fff + ((v >> 16) & 1);
  lo = (unsigned short)(s >> 16);
}

// ---------------------------------------------------------------------------
// Kernel 1: x_gates GEMM (SGEMM-NT, fp32) — unchanged from round 3.
//   C[t][b][g] = sum_k x[(b*T+t)][k] * w_ih[g][k] + b_ih[g], stored [t][b][3072]
// ---------------------------------------------------------------------------
__global__ __launch_bounds__(256, 2) void xgates_gemm(
    const float* __restrict__ A,    // x  [16384][1024]
    const float* __restrict__ Bw,   // w_ih [3072][1024]
    const float* __restrict__ bias, // b_ih [3072]
    float* __restrict__ C)          // [256][64][3072]
{
  constexpr int BM = 128, BN = 128, BK = 32, K = 1024;
  __shared__ float As[BK][BM + 4];
  __shared__ float Bs[BK][BN + 4];
  const int bm = blockIdx.x * BM;
  const int bn = blockIdx.y * BN;
  const int tid = threadIdx.x;
  const int tx = tid & 15;
  const int ty = tid >> 4;

  float acc[8][8];
#pragma unroll
  for (int i = 0; i < 8; i++)
#pragma unroll
    for (int j = 0; j < 8; j++) acc[i][j] = 0.f;

  float4 pa[4], pb[4];
  auto gload = [&](int k0) {
#pragma unroll
    for (int i = 0; i < 4; i++) {
      int idx = tid + i * 256;
      int r   = idx >> 3;
      int c4  = (idx & 7) * 4;
      pa[i] = *reinterpret_cast<const float4*>(&A[(size_t)(bm + r) * K + k0 + c4]);
      pb[i] = *reinterpret_cast<const float4*>(&Bw[(size_t)(bn + r) * K + k0 + c4]);
    }
  };

  gload(0);
  for (int k0 = 0; k0 < K; k0 += BK) {
    if (k0) __syncthreads();
#pragma unroll
    for (int i = 0; i < 4; i++) {
      int idx = tid + i * 256;
      int r   = idx >> 3;
      int c4  = (idx & 7) * 4;
      As[c4 + 0][r] = pa[i].x; As[c4 + 1][r] = pa[i].y;
      As[c4 + 2][r] = pa[i].z; As[c4 + 3][r] = pa[i].w;
      Bs[c4 + 0][r] = pb[i].x; Bs[c4 + 1][r] = pb[i].y;
      Bs[c4 + 2][r] = pb[i].z; Bs[c4 + 3][r] = pb[i].w;
    }
    __syncthreads();
    if (k0 + BK < K) gload(k0 + BK);
#pragma unroll 8
    for (int kk = 0; kk < BK; kk++) {
      float a[8], b[8];
      *reinterpret_cast<float4*>(&a[0]) = *reinterpret_cast<const float4*>(&As[kk][tx * 8]);
      *reinterpret_cast<float4*>(&a[4]) = *reinterpret_cast<const float4*>(&As[kk][tx * 8 + 4]);
      *reinterpret_cast<float4*>(&b[0]) = *reinterpret_cast<const float4*>(&Bs[kk][ty * 8]);
      *reinterpret_cast<float4*>(&b[4]) = *reinterpret_cast<const float4*>(&Bs[kk][ty * 8 + 4]);
#pragma unroll
      for (int i = 0; i < 8; i++)
#pragma unroll
        for (int j = 0; j < 8; j++)
          acc[i][j] = fmaf(a[i], b[j], acc[i][j]);
    }
  }

#pragma unroll
  for (int i = 0; i < 8; i++) {
    int m = bm + tx * 8 + i;
    int b = m >> 8;
    int t = m & 255;
    float* crow = &C[((size_t)t * 64 + b) * G3 + bn + ty * 8];
#pragma unroll
    for (int j4 = 0; j4 < 2; j4++) {
      float4 v;
      v.x = acc[i][j4 * 4 + 0] + bias[bn + ty * 8 + j4 * 4 + 0];
      v.y = acc[i][j4 * 4 + 1] + bias[bn + ty * 8 + j4 * 4 + 1];
      v.z = acc[i][j4 * 4 + 2] + bias[bn + ty * 8 + j4 * 4 + 2];
      v.w = acc[i][j4 * 4 + 3] + bias[bn + ty * 8 + j4 * 4 + 3];
      *reinterpret_cast<float4*>(&crow[j4 * 4]) = v;
    }
  }
}

// ---------------------------------------------------------------------------
// Kernel P: pack w_hh (fp32 [3072][1024]) into MFMA A-fragment bf16 hi/lo.
// Block blk in [0,64) owns units blk*16..+15 across gates g=0..2; per (blk,g)
// m-tile: 32 k-frags. Slot d = ((blk*3+g)*32+kf)*64 + lane holds 8 bf16:
// row m = lane&15 (unit u = blk*16+m, gate-row g*1024+u), k = kf*32 + (lane>>4)*8 + j.
// The same k<->slot bijection is used by the B-frag producer, so any HW k-slot
// permutation cancels in the contraction (only lane-role bits must be right).
// ---------------------------------------------------------------------------
__global__ __launch_bounds__(256) void prep_wfrag(
    const float* __restrict__ w_hh,
    unsigned short* __restrict__ whi,
    unsigned short* __restrict__ wlo)
{
  int d = blockIdx.x * 256 + threadIdx.x; // [0, 64*3*32*64 = 393216)
  int l    = d & 63;
  int slot = d >> 6;       // (blk*3+g)*32 + kf
  int kf   = slot & 31;
  int bg   = slot >> 5;    // blk*3 + g
  int g    = bg % 3;
  int blk  = bg / 3;
  int row  = g * 1024 + blk * 16 + (l & 15);
  int k0   = kf * 32 + (l >> 4) * 8;
  const float* src = w_hh + (size_t)row * 1024 + k0;
  short8 vh, vl;
#pragma unroll
  for (int j = 0; j < 8; j++) {
    unsigned short h, lo;
    bf16_split(src[j], h, lo);
    vh[j] = (short)h;
    vl[j] = (short)lo;
  }
  *reinterpret_cast<short8*>(whi + (size_t)d * 8) = vh;
  *reinterpret_cast<short8*>(wlo + (size_t)d * 8) = vl;
}

// ---------------------------------------------------------------------------
// Kernel 2: one GRU timestep via MFMA (bf16 hi/lo split, fp32-accurate).
// Grid 64 blocks x 256 thr (4 waves). Block owns units u0..u0+15 for ALL 3
// gates (gate math needs r,z,n co-located). Wave wid owns k-slice wid*256.
// Per kf: load A-frags (3 gates x hi/lo) + B-frags (4 n-tiles x hi/lo), do
// 3x4x4 = 48 MFMA. Cross-wave combine in LDS; wave wid finishes n-tile wid:
// gates + writes fp32 mirror ht_out[u][b] AND next step's B-frags (hi/lo).
// B-frag layout: [kf 32][nt 4][lane 64][8 bf16]; element (k,b): lane =
// (k&31>>3)*16 + (b&15), j = k&7  (same bijection as A — see prep_wfrag).
// ---------------------------------------------------------------------------
__global__ __launch_bounds__(256) void gru_step_mfma(
    const float* __restrict__ xg_t,           // [64][3072] this timestep slab
    const float* __restrict__ ht_in,          // [1024][64] fp32 mirror (h_prev)
    float* __restrict__ ht_out,               // [1024][64]
    const unsigned short* __restrict__ whi,   // A-frags hi
    const unsigned short* __restrict__ wlo,   // A-frags lo
    const unsigned short* __restrict__ hhi_in,  // B-frags hi (this step)
    const unsigned short* __restrict__ hlo_in,  // B-frags lo
    unsigned short* __restrict__ hhi_out,       // B-frags hi (next step)
    unsigned short* __restrict__ hlo_out,       // B-frags lo
    const float* __restrict__ b_hh)           // [3072]
{
  __shared__ f32x4 args[3][4][4][64]; // [g][nt][srcwave][lane] = 48 KB
  const int tid  = threadIdx.x;
  const int lane = tid & 63;
  const int wid  = __builtin_amdgcn_readfirstlane(tid >> 6); // 0..3
  const int blk  = blockIdx.x;                               // 0..63
  const int u0   = blk * 16;

  // ---- epilogue operand prefetch (issued early, used at the end) ----
  // C layout (verified m89): col = lane&15 (batch), row = (lane>>4)*4 + reg (unit).
  const int bcol  = wid * 16 + (lane & 15);
  const int urow0 = (lane >> 4) * 4;
  float xr[4], xz[4], xn[4], hprev[4], bhr[4], bhz[4], bhn[4];
#pragma unroll
  for (int r = 0; r < 4; r++) {
    int u = u0 + urow0 + r;
    xr[r]    = xg_t[(size_t)bcol * G3 + u];
    xz[r]    = xg_t[(size_t)bcol * G3 + 1024 + u];
    xn[r]    = xg_t[(size_t)bcol * G3 + 2048 + u];
    hprev[r] = ht_in[(size_t)u * 64 + bcol];
    bhr[r]   = b_hh[u];
    bhz[r]   = b_hh[1024 + u];
    bhn[r]   = b_hh[2048 + u];
  }

  // ---- MFMA main loop: this wave's 8 k-frags (K-slice wid*256..+255) ----
  f32x4 acc[3][4];
#pragma unroll
  for (int g = 0; g < 3; g++)
#pragma unroll
    for (int nt = 0; nt < 4; nt++) acc[g][nt] = (f32x4){0.f, 0.f, 0.f, 0.f};

  for (int kk = 0; kk < 8; kk++) {
    const int kf = wid * 8 + kk;
    short8 Ah[3], Al[3], Bh[4], Bl[4];
#pragma unroll
    for (int g = 0; g < 3; g++) {
      size_t off = ((size_t)((blk * 3 + g) * 32 + kf) * 64 + lane) * 8;
      Ah[g] = *reinterpret_cast<const short8*>(whi + off);
      Al[g] = *reinterpret_cast<const short8*>(wlo + off);
    }
#pragma unroll
    for (int nt = 0; nt < 4; nt++) {
      size_t off = ((size_t)(kf * 4 + nt) * 64 + lane) * 8;
      Bh[nt] = *reinterpret_cast<const short8*>(hhi_in + off);
      Bl[nt] = *reinterpret_cast<const short8*>(hlo_in + off);
    }
#pragma unroll
    for (int g = 0; g < 3; g++)
#pragma unroll
      for (int nt = 0; nt < 4; nt++) {
        acc[g][nt] = mfma16(Ah[g], Bh[nt], acc[g][nt]);
        acc[g][nt] = mfma16(Ah[g], Bl[nt], acc[g][nt]);
        acc[g][nt] = mfma16(Al[g], Bh[nt], acc[g][nt]);
        acc[g][nt] = mfma16(Al[g], Bl[nt], acc[g][nt]);
      }
  }

  // ---- cross-wave K combine ----
#pragma unroll
  for (int g = 0; g < 3; g++)
#pragma unroll
    for (int nt = 0; nt < 4; nt++) args[g][nt][wid][lane] = acc[g][nt];
  __syncthreads();

  f32x4 cg[3];
#pragma unroll
  for (int g = 0; g < 3; g++) {
    f32x4 s = args[g][wid][0][lane];
    s += args[g][wid][1][lane];
    s += args[g][wid][2][lane];
    s += args[g][wid][3][lane];
    cg[g] = s;
  }

  // ---- gate math + dual-format h write ----
#pragma unroll
  for (int r = 0; r < 4; r++) {
    float hr = cg[0][r] + bhr[r];
    float hz = cg[1][r] + bhz[r];
    float hn = cg[2][r] + bhn[r];
    float rr = 1.f / (1.f + expf(-(xr[r] + hr)));
    float zz = 1.f / (1.f + expf(-(xz[r] + hz)));
    float nn = tanhf(xn[r] + rr * hn);
    float h  = (1.f - zz) * nn + zz * hprev[r];

    const int u = u0 + urow0 + r;
    ht_out[(size_t)u * 64 + bcol] = h;

    unsigned short hi, lo;
    bf16_split(h, hi, lo);
    const int kf  = u >> 5;
    const int kin = u & 31;
    const int lp  = ((kin >> 3) << 4) | (bcol & 15); // same bijection as A-pack
    const int nt  = bcol >> 4;
    size_t off = ((size_t)(kf * 4 + nt) * 64 + lp) * 8 + (kin & 7);
    hhi_out[off] = hi;
    hlo_out[off] = lo;
  }
}

// ---------------------------------------------------------------------------
// Kernel 3: small FC over transposed activations (runs once -> not hot).
// ---------------------------------------------------------------------------
template <int LEAKY, int STORE_T>
__global__ __launch_bounds__(256) void fc_kernel(
    const float* __restrict__ At,   // [K][64]
    const float* __restrict__ W,    // [N][K]
    const float* __restrict__ bias, // [N]
    float* __restrict__ out,        // [N][64] if STORE_T else [64][N]
    int N, int K)
{
  constexpr int KC = 128;
  __shared__ float a_s[KC][68];
  const int tid  = threadIdx.x;
  const int lane = tid & 63;
  const int wid  = __builtin_amdgcn_readfirstlane(tid >> 6);
  const int n0   = blockIdx.x * 16 + wid * 4;

  const float* __restrict__ w0 = W + (size_t)(n0 + 0) * K;
  const float* __restrict__ w1 = W + (size_t)(n0 + 1) * K;
  const float* __restrict__ w2 = W + (size_t)(n0 + 2) * K;
  const float* __restrict__ w3 = W + (size_t)(n0 + 3) * K;

  float acc0 = 0.f, acc1 = 0.f, acc2 = 0.f, acc3 = 0.f;
  for (int kc = 0; kc < K; kc += KC) {
#pragma unroll
    for (int i = 0; i < 8; i++) {
      int idx = tid + i * 256;
      int j   = idx >> 4;
      int c4  = (idx & 15) * 4;
      *reinterpret_cast<float4*>(&a_s[j][c4]) =
          *reinterpret_cast<const float4*>(&At[(size_t)(kc + j) * 64 + c4]);
    }
    __syncthreads();
#pragma unroll 16
    for (int j = 0; j < KC; j++) {
      float av = a_s[j][lane];
      acc0 = fmaf(av, w0[kc + j], acc0);
      acc1 = fmaf(av, w1[kc + j], acc1);
      acc2 = fmaf(av, w2[kc + j], acc2);
      acc3 = fmaf(av, w3[kc + j], acc3);
    }
    __syncthreads();
  }
  float r0 = acc0 + bias[n0 + 0];
  float r1 = acc1 + bias[n0 + 1];
  float r2 = acc2 + bias[n0 + 2];
  float r3 = acc3 + bias[n0 + 3];
  if (LEAKY) {
    r0 = (r0 >= 0.f) ? r0 : 0.2f * r0;
    r1 = (r1 >= 0.f) ? r1 : 0.2f * r1;
    r2 = (r2 >= 0.f) ? r2 : 0.2f * r2;
    r3 = (r3 >= 0.f) ? r3 : 0.2f * r3;
  }
  if (STORE_T) {
    out[(size_t)(n0 + 0) * 64 + lane] = r0;
    out[(size_t)(n0 + 1) * 64 + lane] = r1;
    out[(size_t)(n0 + 2) * 64 + lane] = r2;
    out[(size_t)(n0 + 3) * 64 + lane] = r3;
  } else {
    float4 v; v.x = r0; v.y = r1; v.z = r2; v.w = r3;
    *reinterpret_cast<float4*>(&out[(size_t)lane * N + n0]) = v;
  }
}

// ---------------------------------------------------------------------------
// Launch. Workspace (floats):
//   xg      [256][64][3072]                  50,331,648
//   hA,hB   [1024][64] fp32 h mirrors            65,536 x2
//   y1      [1024][64]                           65,536
//   whi,wlo A-frags 3072x1024 bf16            1,572,864 x2
//   hfrag   4 x (32*4*64*8 ushort)               32,768 x4  (hi0,lo0,hi1,lo1)
// Total ~215.4 MB.
// ---------------------------------------------------------------------------
extern "C" void kernel_launch(void* const* d_in, const int* in_sizes, int n_in,
                              void* d_out, int out_size, void* d_ws, size_t ws_size,
                              hipStream_t stream) {
  (void)in_sizes; (void)n_in; (void)out_size; (void)ws_size;
  const float* x    = (const float*)d_in[0];
  const float* w_ih = (const float*)d_in[1];
  const float* w_hh = (const float*)d_in[2];
  const float* b_ih = (const float*)d_in[3];
  const float* b_hh = (const float*)d_in[4];
  const float* w1   = (const float*)d_in[5];
  const float* b1   = (const float*)d_in[6];
  const float* w2   = (const float*)d_in[7];
  const float* b2   = (const float*)d_in[8];
  float* out = (float*)d_out;

  float* ws = (float*)d_ws;
  float* xg = ws;                                   // [256][64][3072]
  float* hA = xg + (size_t)T_ * B_ * G3;            // fp32 h mirror A
  float* hB = hA + (size_t)H_ * B_;                 // fp32 h mirror B
  float* y1 = hB + (size_t)H_ * B_;                 // fc1 out [1024][64]
  unsigned short* whi = (unsigned short*)(y1 + (size_t)H_ * B_);
  unsigned short* wlo = whi + (size_t)G3 * H_;      // 3,145,728 ushorts each
  unsigned short* hf  = wlo + (size_t)G3 * H_;      // 4 frag buffers, 65,536 each
  unsigned short* hhi0 = hf;
  unsigned short* hlo0 = hhi0 + 65536;
  unsigned short* hhi1 = hlo0 + 65536;
  unsigned short* hlo1 = hhi1 + 65536;

  // h0 = 0: fp32 mirror + step-0 input frags (hhi0,hlo0 contiguous).
  hipMemsetAsync(hA, 0, (size_t)H_ * B_ * sizeof(float), stream);
  hipMemsetAsync(hhi0, 0, 2 * 65536 * sizeof(unsigned short), stream);

  prep_wfrag<<<1536, 256, 0, stream>>>(w_hh, whi, wlo);
  xgates_gemm<<<dim3(128, 24), 256, 0, stream>>>(x, w_ih, b_ih, xg);

  for (int t = 0; t < T_; t++) {
    const float* hin  = (t & 1) ? hB : hA;
    float*       hout = (t & 1) ? hA : hB;
    const unsigned short* fhi_in  = (t & 1) ? hhi1 : hhi0;
    const unsigned short* flo_in  = (t & 1) ? hlo1 : hlo0;
    unsigned short*       fhi_out = (t & 1) ? hhi0 : hhi1;
    unsigned short*       flo_out = (t & 1) ? hlo0 : hlo1;
    gru_step_mfma<<<64, 256, 0, stream>>>(xg + (size_t)t * B_ * G3, hin, hout,
                                          whi, wlo, fhi_in, flo_in, fhi_out, flo_out,
                                          b_hh);
  }
  // T=256 even -> final h lives in hA.
  fc_kernel<1, 1><<<64, 256, 0, stream>>>(hA, w1, b1, y1, H_, H_);
  fc_kernel<0, 0><<<64, 256, 0, stream>>>(y1, w2, b2, out, E_, H_);
}